// Round 4
// baseline (83432.623 us; speedup 1.0000x reference)
//
// v4: LDS-resident weights sized to fit hipLaunchCooperativeKernel capacity
// (<=32KB LDS/block, 506 blocks <= 2/CU * 256). Launch return code checked;
// verbatim round-0 kernel as fallback. Bit-exact association preserved.
#include <hip/hip_runtime.h>
#include <hip/hip_cooperative_groups.h>

namespace cg = cooperative_groups;

#define UNITS 3225
#define NBATCH 64
#define NSTEP 500
#define NH_SCALE 0.004472135954999579f   // 0.01*sqrt(2*0.1)
#define NI_SCALE 0.004472135954999579f
#define WC_FLOATS 2699776
#define HSZ 103200000ll                  // 64*500*3225

// region tables: str, fsi, gpe, stn, snr, thal, alm
__constant__ int   c_dst[7]  = {0,512,665,1177,1689,2201,2713};
__constant__ int   c_rows[7] = {512,153,512,512,512,512,512};
__constant__ int   c_wid[7]  = {1536,1024,256,512,768,871,1024};
__constant__ int   c_base[7] = {0,786432,943104,1074176,1336320,1729536,2175488};
__constant__ int   c_r0s[7]  = {0,512,256,665,0,1689,2201};
__constant__ int   c_r0l[7]  = {665,153,256,512,256,512,1024};
__constant__ int   c_r1s[7]  = {2201,2201,0,0,1177,2713,0};
__constant__ float c_ton[7]  = {0.1f,0.1f,0.6f,0.3f,0.6f,0.1f,0.1f};
__constant__ int   c_cbase[8]= {0,786432,943104,1074176,1336320,1729536,2175488,2699776};

// v4 partition: rows/block, padded LDS row-stride (even), block prefix
__constant__ int   c4_rpb[7]  = {4,6,14,9,6,6,6};
__constant__ int   c4_rstr[7] = {4,6,14,10,6,6,6};
__constant__ int   c4_cs[8]   = {0,128,154,191,248,334,420,506};
#define NBLK4 506
#define NTHR4 512

// round-0 fallback partition (8 rows/block everywhere)
__constant__ int   c0_cs[8]   = {0,64,84,148,212,276,340,404};

__device__ __forceinline__ float ht_clip(float w) {
    return fminf(fmaxf(w, 1e-10f), 1.0f);
}

__global__ void build_w_v4(
    const float* __restrict__ str2str, const float* __restrict__ thal2alm,
    const float* __restrict__ thal2str, const float* __restrict__ alm2alm,
    const float* __restrict__ alm2str, const float* __restrict__ alm2thal,
    const float* __restrict__ str2snr, const float* __restrict__ str2gpe,
    const float* __restrict__ gpe2stn, const float* __restrict__ stn2snr,
    const float* __restrict__ snr2thal, const float* __restrict__ fsi2str,
    const float* __restrict__ thal2fsi, const float* __restrict__ alm2fsi,
    const float* __restrict__ fsi2fsi, const int* __restrict__ smask,
    float* __restrict__ Wc)
{
    int tid = blockIdx.x * blockDim.x + threadIdx.x;
    if (tid >= WC_FLOATS) return;
    int r = 0;
    while (tid >= c_cbase[r+1]) ++r;
    int local = tid - c_cbase[r];
    int width = c_wid[r];
    int row = local / width;
    int c = local - row * width;
    int r0l = c_r0l[r];
    int v = (c < r0l) ? (c_r0s[r] + c) : (c_r1s[r] + (c - r0l));
    int i = row;
    int rv, j;
    if (v < 512)       { rv = 0; j = v; }
    else if (v < 665)  { rv = 1; j = v - 512; }
    else if (v < 1177) { rv = 2; j = v - 665; }
    else if (v < 1689) { rv = 3; j = v - 1177; }
    else if (v < 2201) { rv = 4; j = v - 1689; }
    else if (v < 2713) { rv = 5; j = v - 2201; }
    else               { rv = 6; j = v - 2713; }
    float val = 0.0f;
    switch (r) {
    case 0:
        if (rv == 0)      val = smask[i*512+j] ? -ht_clip(str2str[i*512+j]) : 0.0f;
        else if (rv == 1) val = -ht_clip(fsi2str[i*153+j]);
        else if (rv == 5) val = (i < 256) ? ht_clip(thal2str[i*512+j]) : 0.0f;
        else              val = (j < 359) ? ht_clip(alm2str[i*512+j]) : 0.0f;
        break;
    case 1:
        if (rv == 1)      val = -ht_clip(fsi2fsi[i*153+j]);
        else if (rv == 5) val = ht_clip(thal2fsi[i*512+j]);
        else              val = (j < 359) ? ht_clip(alm2fsi[i*512+j]) : 0.0f;
        break;
    case 2:
        val = (j >= 256) ? -ht_clip(str2gpe[i*512+j]) : 0.0f;
        break;
    case 3:
        val = -ht_clip(gpe2stn[i*512+j]);
        break;
    case 4:
        if (rv == 0) val = (j < 256) ? -ht_clip(str2snr[i*512+j]) : 0.0f;
        else         val = ht_clip(stn2snr[i*512+j]);
        break;
    case 5:
        if (rv == 4) val = -ht_clip(snr2thal[i*512+j]);
        else         val = (j < 359) ? ht_clip(alm2thal[i*512+j]) : 0.0f;
        break;
    default:
        if (rv == 5) val = ht_clip(thal2alm[i*512+j]);
        else         val = (j < 359) ? ht_clip(alm2alm[i*512+j]) : -ht_clip(alm2alm[i*512+j]);
        break;
    }
    Wc[tid] = val;
}

struct Params {
    const float* inp;
    const float* cue;
    const float* inhib;
    const float* hn;
    const float* xn;
    const float* noise_hid;
    const float* noise_inp;
    const float* inp_w;
    const float* out_w;
    const float* Wc;
    float* hT0;
    float* hT1;
    float* out;
};

// =====================  v4 kernel  =====================
// 8 waves = 2 row-pair-groups x 4 K-quarters. Weights LDS-resident,
// transposed [c][row], rows padded (zeros) to even stride rstr.
// BIT-EXACTNESS CONTRACT (vs round-0): quarter boundaries (width*kq)>>2,
// segment-A-then-B ascending c, one acc chain per (row,quarter), quarters
// summed ascending, drive order mm+tonic -> inp -> cue -> inhib -> noise.
__global__ void __launch_bounds__(NTHR4, 4) rnn_loop_v4(Params p)
{
    cg::grid_group grid = cg::this_grid();
    const int tid  = threadIdx.x;
    const int lane = tid & 63;
    const int wv   = tid >> 6;          // 0..7
    const int kq   = wv & 3;            // K-quarter
    const int grp  = wv >> 2;           // row-pair group
    const int bi   = blockIdx.x;

    int r = 0;
    while (bi >= c4_cs[r+1]) ++r;
    const int lc    = bi - c4_cs[r];
    const int rpb   = c4_rpb[r];
    const int rstr  = c4_rstr[r];
    const int row0  = lc * rpb;
    const int nr    = min(rpb, c_rows[r] - row0);
    const int u0    = c_dst[r] + row0;
    const int width = c_wid[r];
    const float tonic = c_ton[r];
    const int r0s = c_r0s[r], r0l = c_r0l[r], r1s = c_r1s[r];
    const float* wr = p.Wc + c_base[r] + (long long)row0 * width;

    __shared__ __align__(16) float lds[8192];     // exactly 32KB -> 2 blocks/CU
    float* w_lds = lds;                            // [c*rstr + q]
    float* redb  = lds + width * rstr;             // [(kq*nr + rr)*64 + lane]
    float* htile = redb + 4 * nr * 64;             // [rr*65 + b]

    // one-time: stage weights to LDS, transposed [c][row]; zero-pad rows
    for (int q = 0; q < nr; ++q)
        for (int c = tid; c < width; c += NTHR4)
            w_lds[c*rstr + q] = wr[q*width + c];
    for (int q = nr; q < rstr; ++q)
        for (int c = tid; c < width; c += NTHR4)
            w_lds[c*rstr + q] = 0.0f;

    // pair range for this wave's group
    const int np    = rstr >> 1;
    const int p0    = (np + 1) >> 1;
    const int plo   = grp ? p0 : 0;
    const int npair = (grp ? np : p0) - plo;       // 1..4

    // x state in registers: rows wv and wv+8
    float xr0 = 0.0f, xr1 = 0.0f;
    if (wv < nr) {
        int u = u0 + wv;
        xr0 = p.xn[lane*UNITS + u];
        p.hT0[u*64 + lane] = p.hn[lane*UNITS + u];
    }
    if (wv + 8 < nr) {
        int u = u0 + wv + 8;
        xr1 = p.xn[lane*UNITS + u];
        p.hT0[u*64 + lane] = p.hn[lane*UNITS + u];
    }
    const bool outs_block = (bi >= 442);   // last 64 alm blocks do readout
    const int  ob = bi - 442;
    __syncthreads();
    grid.sync();

    for (int t = 0; t < NSTEP; ++t) {
        const float* __restrict__ rb = (t & 1) ? p.hT1 : p.hT0;
        float* __restrict__ wb = (t & 1) ? p.hT0 : p.hT1;

        // readout for previous step (h(t-1) lives in rb)
        if (outs_block && t > 0 && tid < 64) {
            float s = 0.0f;
            for (int jj = lane; jj < 359; jj += 64)
                s += rb[(2713+jj)*64 + ob] * p.out_w[jj];
            #pragma unroll
            for (int off = 32; off > 0; off >>= 1)
                s += __shfl_down(s, off, 64);
            if (lane == 0) p.out[HSZ + (long long)ob*NSTEP + (t-1)] = s;
        }

        // prefetch strided per-step inputs; latency hides under matmul
        float nh0 = 0.0f, ih0 = 0.0f, nh1 = 0.0f, ih1 = 0.0f;
        if (wv < nr) {
            int u = u0 + wv;
            nh0 = __builtin_nontemporal_load(&p.noise_hid[((long long)t*NBATCH + lane)*UNITS + u]);
            ih0 = __builtin_nontemporal_load(&p.inhib[((long long)lane*NSTEP + t)*UNITS + u]);
        }
        if (wv + 8 < nr) {
            int u = u0 + wv + 8;
            nh1 = __builtin_nontemporal_load(&p.noise_hid[((long long)t*NBATCH + lane)*UNITS + u]);
            ih1 = __builtin_nontemporal_load(&p.inhib[((long long)lane*NSTEP + t)*UNITS + u]);
        }
        const float inp_eff = p.inp[lane*NSTEP + t] + NI_SCALE * p.noise_inp[t*NBATCH + lane];
        const float cue_b   = p.cue[lane*NSTEP + t];

        // ---- matmul: this wave = (pair group, K quarter) ----
        const int c0 = (width * kq) >> 2;
        const int c1 = (width * (kq + 1)) >> 2;
        const int a1 = min(c1, r0l);
        const int b0 = max(c0, r0l);
        float acc[8];
        #pragma unroll
        for (int i = 0; i < 8; ++i) acc[i] = 0.0f;
        const float2* __restrict__ w2 = (const float2*)w_lds;

        #pragma unroll 2
        for (int c = c0; c < a1; ++c) {
            float hv = rb[(r0s + c)*64 + lane];
            #pragma unroll
            for (int pp = 0; pp < 4; ++pp)
                if (pp < npair) {
                    float2 f = w2[c*np + plo + pp];
                    acc[2*pp]   += f.x * hv;
                    acc[2*pp+1] += f.y * hv;
                }
        }
        #pragma unroll 2
        for (int c = b0; c < c1; ++c) {
            float hv = rb[(r1s + (c - r0l))*64 + lane];
            #pragma unroll
            for (int pp = 0; pp < 4; ++pp)
                if (pp < npair) {
                    float2 f = w2[c*np + plo + pp];
                    acc[2*pp]   += f.x * hv;
                    acc[2*pp+1] += f.y * hv;
                }
        }
        #pragma unroll
        for (int pp = 0; pp < 4; ++pp)
            if (pp < npair) {
                int rr = 2*(plo + pp);
                if (rr < nr)     redb[(kq*nr + rr)*64 + lane]     = acc[2*pp];
                if (rr + 1 < nr) redb[(kq*nr + rr + 1)*64 + lane] = acc[2*pp+1];
            }
        __syncthreads();

        // ---- reduce quarters (ascending) + pointwise: rows wv, wv+8 ----
        if (wv < nr) {
            int rr = wv, u = u0 + rr;
            float mm = redb[(0*nr + rr)*64 + lane];
            mm += redb[(1*nr + rr)*64 + lane];
            mm += redb[(2*nr + rr)*64 + lane];
            mm += redb[(3*nr + rr)*64 + lane];
            float drive = mm + tonic;
            if (u < 665) drive += inp_eff * p.inp_w[u];
            if (u >= 2201 && u < 2713) drive += cue_b;
            drive += ih0;
            drive += NH_SCALE * nh0;
            xr0 = xr0 + 0.1f*(drive - xr0);
            float h = fmaxf(xr0, 0.0f);
            wb[u*64 + lane] = h;
            htile[rr*65 + lane] = h;
        }
        if (wv + 8 < nr) {
            int rr = wv + 8, u = u0 + rr;
            float mm = redb[(0*nr + rr)*64 + lane];
            mm += redb[(1*nr + rr)*64 + lane];
            mm += redb[(2*nr + rr)*64 + lane];
            mm += redb[(3*nr + rr)*64 + lane];
            float drive = mm + tonic;
            if (u < 665) drive += inp_eff * p.inp_w[u];
            if (u >= 2201 && u < 2713) drive += cue_b;
            drive += ih1;
            drive += NH_SCALE * nh1;
            xr1 = xr1 + 0.1f*(drive - xr1);
            float h = fmaxf(xr1, 0.0f);
            wb[u*64 + lane] = h;
            htile[rr*65 + lane] = h;
        }
        __syncthreads();
        {
            // hs output: [b][t][u]; rows 0..15, batches in two halves
            int rr = tid & 15, bb = tid >> 4;   // bb 0..31
            if (rr < nr) {
                long long o = (long long)bb*(NSTEP*UNITS) + (long long)t*UNITS + (u0+rr);
                __builtin_nontemporal_store(htile[rr*65 + bb], &p.out[o]);
                __builtin_nontemporal_store(htile[rr*65 + bb + 32], &p.out[o + 32ll*NSTEP*UNITS]);
            }
        }
        grid.sync();
    }

    if (outs_block && tid < 64) {
        const float* __restrict__ rb = p.hT0;   // h(499): 500 even
        float s = 0.0f;
        for (int jj = lane; jj < 359; jj += 64)
            s += rb[(2713+jj)*64 + ob] * p.out_w[jj];
        #pragma unroll
        for (int off = 32; off > 0; off >>= 1)
            s += __shfl_down(s, off, 64);
        if (lane == 0) p.out[HSZ + (long long)ob*NSTEP + (NSTEP-1)] = s;
    }
}

// =====================  round-0 fallback (verbatim logic)  =====================
__global__ void __launch_bounds__(256) rnn_loop_fb(Params p)
{
    cg::grid_group grid = cg::this_grid();
    const int tid  = threadIdx.x;
    const int lane = tid & 63;
    const int wv   = tid >> 6;
    const int bi   = blockIdx.x;

    int r = 0;
    while (bi >= c0_cs[r+1]) ++r;
    const int lc    = bi - c0_cs[r];
    const int row0  = lc * 8;
    const int nr    = min(8, c_rows[r] - row0);
    const int u0    = c_dst[r] + row0;
    const int width = c_wid[r];
    const float tonic = c_ton[r];
    const int r0s = c_r0s[r], r0l = c_r0l[r], r1s = c_r1s[r];
    const float* __restrict__ wr = p.Wc + c_base[r] + row0 * width;

    __shared__ float red[4][8][64];
    __shared__ float htile[8*65];

    const int r2 = tid >> 6;
    const int b  = tid & 63;

    float xreg[2];
    #pragma unroll
    for (int pi = 0; pi < 2; ++pi) {
        int pr = r2 + 4*pi;
        xreg[pi] = 0.0f;
        if (pr < nr) {
            xreg[pi] = p.xn[b*UNITS + (u0+pr)];
            p.hT0[(u0+pr)*64 + b] = p.hn[b*UNITS + (u0+pr)];
        }
    }
    const bool outs_block = (bi >= 84 && bi < 148);
    grid.sync();

    const int c0 = (width * wv) >> 2;
    const int c1 = (width * (wv+1)) >> 2;
    const int a0 = c0, a1 = min(c1, r0l);
    const int b0 = max(c0, r0l), b1 = c1;

    for (int t = 0; t < NSTEP; ++t) {
        const float* __restrict__ rb = (t & 1) ? p.hT1 : p.hT0;
        float* __restrict__ wb = (t & 1) ? p.hT0 : p.hT1;

        if (outs_block && t > 0 && tid < 64) {
            int ob = bi - 84;
            float s = 0.0f;
            for (int jj = lane; jj < 359; jj += 64)
                s += rb[(2713+jj)*64 + ob] * p.out_w[jj];
            #pragma unroll
            for (int off = 32; off > 0; off >>= 1)
                s += __shfl_down(s, off, 64);
            if (lane == 0) p.out[HSZ + (long long)ob*NSTEP + (t-1)] = s;
        }

        float acc[8];
        #pragma unroll
        for (int q = 0; q < 8; ++q) acc[q] = 0.0f;

        #pragma unroll 4
        for (int c = a0; c < a1; ++c) {
            float hv = rb[(r0s + c)*64 + lane];
            #pragma unroll
            for (int q = 0; q < 8; ++q) acc[q] += wr[q*width + c] * hv;
        }
        #pragma unroll 4
        for (int c = b0; c < b1; ++c) {
            float hv = rb[(r1s + (c - r0l))*64 + lane];
            #pragma unroll
            for (int q = 0; q < 8; ++q) acc[q] += wr[q*width + c] * hv;
        }

        #pragma unroll
        for (int q = 0; q < 8; ++q) red[wv][q][lane] = acc[q];
        __syncthreads();

        const float inp_eff = p.inp[b*NSTEP + t] + NI_SCALE * p.noise_inp[t*NBATCH + b];
        const float cue_b   = p.cue[b*NSTEP + t];
        #pragma unroll
        for (int pi = 0; pi < 2; ++pi) {
            int pr = r2 + 4*pi;
            if (pr < nr) {
                int u = u0 + pr;
                float mm = red[0][pr][b] + red[1][pr][b] + red[2][pr][b] + red[3][pr][b];
                float drive = mm + tonic;
                if (u < 665) drive += inp_eff * p.inp_w[u];
                if (u >= 2201 && u < 2713) drive += cue_b;
                drive += p.inhib[((long long)b*NSTEP + t)*UNITS + u];
                drive += NH_SCALE * p.noise_hid[((long long)t*NBATCH + b)*UNITS + u];
                float xv = xreg[pi];
                xv = xv + 0.1f*(drive - xv);
                xreg[pi] = xv;
                float h = fmaxf(xv, 0.0f);
                wb[u*64 + b] = h;
                htile[pr*65 + b] = h;
            }
        }
        __syncthreads();
        {
            int rr = tid & 7, bb = tid >> 3;
            if (rr < nr) {
                long long o = (long long)bb*(NSTEP*UNITS) + (long long)t*UNITS + (u0+rr);
                p.out[o] = htile[rr*65 + bb];
                p.out[o + 32ll*NSTEP*UNITS] = htile[rr*65 + bb + 32];
            }
        }
        grid.sync();
    }

    if (outs_block && tid < 64) {
        int ob = bi - 84;
        const float* __restrict__ rb = p.hT0;
        float s = 0.0f;
        for (int jj = lane; jj < 359; jj += 64)
            s += rb[(2713+jj)*64 + ob] * p.out_w[jj];
        #pragma unroll
        for (int off = 32; off > 0; off >>= 1)
            s += __shfl_down(s, off, 64);
        if (lane == 0) p.out[HSZ + (long long)ob*NSTEP + (NSTEP-1)] = s;
    }
}

extern "C" void kernel_launch(void* const* d_in, const int* in_sizes, int n_in,
                              void* d_out, int out_size, void* d_ws, size_t ws_size,
                              hipStream_t stream)
{
    (void)in_sizes; (void)n_in; (void)out_size; (void)ws_size;
    const float* inp       = (const float*)d_in[0];
    const float* cue       = (const float*)d_in[1];
    const float* inhib     = (const float*)d_in[2];
    const float* hn        = (const float*)d_in[3];
    const float* xn        = (const float*)d_in[4];
    const float* noise_hid = (const float*)d_in[5];
    const float* noise_inp = (const float*)d_in[6];
    const float* str2str   = (const float*)d_in[7];
    const float* thal2alm  = (const float*)d_in[8];
    const float* thal2str  = (const float*)d_in[9];
    const float* alm2alm   = (const float*)d_in[10];
    const float* alm2str   = (const float*)d_in[11];
    const float* alm2thal  = (const float*)d_in[12];
    const float* str2snr   = (const float*)d_in[13];
    const float* str2gpe   = (const float*)d_in[14];
    const float* gpe2stn   = (const float*)d_in[15];
    const float* stn2snr   = (const float*)d_in[16];
    const float* snr2thal  = (const float*)d_in[17];
    const float* fsi2str   = (const float*)d_in[18];
    const float* thal2fsi  = (const float*)d_in[19];
    const float* alm2fsi   = (const float*)d_in[20];
    const float* fsi2fsi   = (const float*)d_in[21];
    const float* inp_w     = (const float*)d_in[22];
    const float* out_w     = (const float*)d_in[23];
    const int*   smask     = (const int*)d_in[24];

    float* Wc  = (float*)d_ws;                 // 2,699,776 floats (10.8 MB)
    float* hT0 = Wc + WC_FLOATS;               // [UNITS][64]
    float* hT1 = hT0 + UNITS*64;               // ping-pong buffer

    hipLaunchKernelGGL(build_w_v4, dim3((WC_FLOATS+255)/256), dim3(256), 0, stream,
        str2str, thal2alm, thal2str, alm2alm, alm2str, alm2thal, str2snr, str2gpe,
        gpe2stn, stn2snr, snr2thal, fsi2str, thal2fsi, alm2fsi, fsi2fsi, smask, Wc);

    Params p;
    p.inp = inp; p.cue = cue; p.inhib = inhib; p.hn = hn; p.xn = xn;
    p.noise_hid = noise_hid; p.noise_inp = noise_inp;
    p.inp_w = inp_w; p.out_w = out_w; p.Wc = Wc;
    p.hT0 = hT0; p.hT1 = hT1; p.out = (float*)d_out;

    void* kargs[] = { &p };
    hipError_t ce = hipLaunchCooperativeKernel((void*)rnn_loop_v4,
                                               dim3(NBLK4), dim3(NTHR4), kargs, 0, stream);
    if (ce != hipSuccess) {
        (void)hipGetLastError();   // clear error state
        hipLaunchCooperativeKernel((void*)rnn_loop_fb,
                                   dim3(404), dim3(256), kargs, 0, stream);
    }
}

// Round 5
// 41872.290 us; speedup vs baseline: 1.9925x; 1.9925x over previous
//
// v5: transposed h ([batch][padded unit], float4 loads), transposed weights in
// DRAM, 125 fat blocks (barrier cost scales with block count), bit-exact
// association preserved (verified by v4's exact absmax match). Round-0
// fallback behind a launch-error check.
#include <hip/hip_runtime.h>
#include <hip/hip_cooperative_groups.h>

namespace cg = cooperative_groups;

#define UNITS 3225
#define HSTR  3232                       // padded h row stride (floats)
#define NBATCH 64
#define NSTEP 500
#define NH_SCALE 0.004472135954999579f   // 0.01*sqrt(2*0.1)
#define NI_SCALE 0.004472135954999579f
#define HSZ 103200000ll                  // 64*500*3225
#define WCT_FLOATS 2731520               // v5 transposed weights
#define WC0_FLOATS 2699776               // round-0 weights (fallback)
#define NBLK5 125
#define NTHR5 512

// ---- original geometry (build + fallback) ----
__constant__ int   c_dst[7]  = {0,512,665,1177,1689,2201,2713};
__constant__ int   c_rows[7] = {512,153,512,512,512,512,512};
__constant__ int   c_wid[7]  = {1536,1024,256,512,768,871,1024};
__constant__ int   c_r0s[7]  = {0,512,256,665,0,1689,2201};
__constant__ int   c_r0l[7]  = {665,153,256,512,256,512,1024};
__constant__ int   c_r1s[7]  = {2201,2201,0,0,1177,2713,0};
__constant__ float c_ton[7]  = {0.1f,0.1f,0.6f,0.3f,0.6f,0.1f,0.1f};

// ---- v5 partition: str,fsi,gpe,stn,snr,thal,alm ----
__constant__ int   c5_rpb[7]  = {16,24,32,32,32,32,24};
__constant__ int   c5_cs[8]   = {0,32,39,55,71,87,103,125};
__constant__ int   c5_wb[8]   = {0,786432,958464,1089536,1351680,1744896,2190848,2731520};
__constant__ int   c5_pdst[7] = {0,512,668,1180,1692,2204,2716};   // padded region starts
__constant__ int   c5_pr0s[7] = {0,512,256,668,0,1692,2204};       // padded segment-A starts
__constant__ int   c5_pr1s[7] = {2204,2204,0,0,1180,2716,2716};    // padded segment-B starts

// ---- round-0 fallback tables ----
__constant__ int   c0_cs[8]   = {0,64,84,148,212,276,340,404};
__constant__ int   c0_base[7] = {0,786432,943104,1074176,1336320,1729536,2175488};
__constant__ int   c0_cbase[8]= {0,786432,943104,1074176,1336320,1729536,2175488,2699776};

__device__ __forceinline__ float ht_clip(float w) {
    return fminf(fmaxf(w, 1e-10f), 1.0f);
}

// shared weight-value computation: region r, row-in-region i, compact col c
__device__ __forceinline__ float w_val(
    int r, int i, int c,
    const float* __restrict__ str2str, const float* __restrict__ thal2alm,
    const float* __restrict__ thal2str, const float* __restrict__ alm2alm,
    const float* __restrict__ alm2str, const float* __restrict__ alm2thal,
    const float* __restrict__ str2snr, const float* __restrict__ str2gpe,
    const float* __restrict__ gpe2stn, const float* __restrict__ stn2snr,
    const float* __restrict__ snr2thal, const float* __restrict__ fsi2str,
    const float* __restrict__ thal2fsi, const float* __restrict__ alm2fsi,
    const float* __restrict__ fsi2fsi, const int* __restrict__ smask)
{
    int r0l = c_r0l[r];
    int v = (c < r0l) ? (c_r0s[r] + c) : (c_r1s[r] + (c - r0l));
    int rv, j;
    if (v < 512)       { rv = 0; j = v; }
    else if (v < 665)  { rv = 1; j = v - 512; }
    else if (v < 1177) { rv = 2; j = v - 665; }
    else if (v < 1689) { rv = 3; j = v - 1177; }
    else if (v < 2201) { rv = 4; j = v - 1689; }
    else if (v < 2713) { rv = 5; j = v - 2201; }
    else               { rv = 6; j = v - 2713; }
    float val = 0.0f;
    switch (r) {
    case 0:
        if (rv == 0)      val = smask[i*512+j] ? -ht_clip(str2str[i*512+j]) : 0.0f;
        else if (rv == 1) val = -ht_clip(fsi2str[i*153+j]);
        else if (rv == 5) val = (i < 256) ? ht_clip(thal2str[i*512+j]) : 0.0f;
        else              val = (j < 359) ? ht_clip(alm2str[i*512+j]) : 0.0f;
        break;
    case 1:
        if (rv == 1)      val = -ht_clip(fsi2fsi[i*153+j]);
        else if (rv == 5) val = ht_clip(thal2fsi[i*512+j]);
        else              val = (j < 359) ? ht_clip(alm2fsi[i*512+j]) : 0.0f;
        break;
    case 2:
        val = (j >= 256) ? -ht_clip(str2gpe[i*512+j]) : 0.0f;
        break;
    case 3:
        val = -ht_clip(gpe2stn[i*512+j]);
        break;
    case 4:
        if (rv == 0) val = (j < 256) ? -ht_clip(str2snr[i*512+j]) : 0.0f;
        else         val = ht_clip(stn2snr[i*512+j]);
        break;
    case 5:
        if (rv == 4) val = -ht_clip(snr2thal[i*512+j]);
        else         val = (j < 359) ? ht_clip(alm2thal[i*512+j]) : 0.0f;
        break;
    default:
        if (rv == 5) val = ht_clip(thal2alm[i*512+j]);
        else         val = (j < 359) ? ht_clip(alm2alm[i*512+j]) : -ht_clip(alm2alm[i*512+j]);
        break;
    }
    return val;
}

#define WARGS                                                                  \
    const float* __restrict__ str2str, const float* __restrict__ thal2alm,     \
    const float* __restrict__ thal2str, const float* __restrict__ alm2alm,     \
    const float* __restrict__ alm2str, const float* __restrict__ alm2thal,     \
    const float* __restrict__ str2snr, const float* __restrict__ str2gpe,      \
    const float* __restrict__ gpe2stn, const float* __restrict__ stn2snr,      \
    const float* __restrict__ snr2thal, const float* __restrict__ fsi2str,     \
    const float* __restrict__ thal2fsi, const float* __restrict__ alm2fsi,     \
    const float* __restrict__ fsi2fsi, const int* __restrict__ smask
#define WPASS str2str, thal2alm, thal2str, alm2alm, alm2str, alm2thal,         \
    str2snr, str2gpe, gpe2stn, stn2snr, snr2thal, fsi2str, thal2fsi, alm2fsi,  \
    fsi2fsi, smask

// v5: weights transposed per block: Wct[blockbase + c*rpb + q]
__global__ void build_w_v5(WARGS, float* __restrict__ Wct)
{
    int tid = blockIdx.x * blockDim.x + threadIdx.x;
    if (tid >= WCT_FLOATS) return;
    int r = 0;
    while (tid >= c5_wb[r+1]) ++r;
    int local = tid - c5_wb[r];
    int rpb   = c5_rpb[r];
    int width = c_wid[r];
    int bsz   = width * rpb;
    int blk   = local / bsz;
    int rem   = local - blk*bsz;
    int c     = rem / rpb;
    int q     = rem - c*rpb;
    int i     = blk*rpb + q;
    float val = 0.0f;
    if (i < c_rows[r]) val = w_val(r, i, c, WPASS);
    Wct[tid] = val;
}

// round-0 layout (fallback): Wc[blockrowbase + q*width + c]
__global__ void build_w_r0(WARGS, float* __restrict__ Wc)
{
    int tid = blockIdx.x * blockDim.x + threadIdx.x;
    if (tid >= WC0_FLOATS) return;
    int r = 0;
    while (tid >= c0_cbase[r+1]) ++r;
    int local = tid - c0_cbase[r];
    int width = c_wid[r];
    int row = local / width;
    int c = local - row * width;
    Wc[tid] = w_val(r, row, c, WPASS);
}

struct Params {
    const float* __restrict__ inp;
    const float* __restrict__ cue;
    const float* __restrict__ inhib;
    const float* __restrict__ hn;
    const float* __restrict__ xn;
    const float* __restrict__ noise_hid;
    const float* __restrict__ noise_inp;
    const float* __restrict__ inp_w;
    const float* __restrict__ out_w;
    const float* __restrict__ Wc;
    float* __restrict__ hT0;
    float* __restrict__ hT1;
    float* __restrict__ out;
};

// BIT-EXACTNESS CONTRACT (verified by v4's exact absmax match): per (row,
// quarter) one acc chain, segment A then B, strictly ascending c; quarters
// summed ascending; drive order mm+tonic -> inp -> cue -> inhib -> noise.
// float4 batching of hv does NOT reorder the chain (x,y,z,w consumed in order).
template<int RPB, int HALF>
__device__ __forceinline__ void mm_seg(
    const float* __restrict__ rbb,   // rb + lane*HSTR  (this lane's batch row)
    const float* __restrict__ wq,    // Wct block base + q0
    int cfrom, int cto, int abase,   // h address = abase + c (padded units)
    float* __restrict__ acc)
{
    int c = cfrom;
    while (c < cto && ((abase + c) & 3)) {          // peel to 16B alignment
        float hv = rbb[abase + c];
        #pragma unroll
        for (int q = 0; q < HALF; ++q) acc[q] += wq[c*RPB + q] * hv;
        ++c;
    }
    #pragma unroll 2
    for (; c + 4 <= cto; c += 4) {
        const float4 h4 = *reinterpret_cast<const float4*>(&rbb[abase + c]);
        const float hvv[4] = {h4.x, h4.y, h4.z, h4.w};
        #pragma unroll
        for (int cc = 0; cc < 4; ++cc) {
            #pragma unroll
            for (int g = 0; g < HALF/4; ++g) {
                const float4 w4 = *reinterpret_cast<const float4*>(&wq[(c+cc)*RPB + 4*g]);
                acc[4*g+0] += w4.x * hvv[cc];
                acc[4*g+1] += w4.y * hvv[cc];
                acc[4*g+2] += w4.z * hvv[cc];
                acc[4*g+3] += w4.w * hvv[cc];
            }
        }
    }
    for (; c < cto; ++c) {                          // tail
        float hv = rbb[abase + c];
        #pragma unroll
        for (int q = 0; q < HALF; ++q) acc[q] += wq[c*RPB + q] * hv;
    }
}

template<int RPB, int HALF>
__device__ __forceinline__ void mm_do(
    const float* __restrict__ rbb, const float* __restrict__ wq,
    int c0, int a1, int b0, int c1, int pr0s, int pr1s, int r0l,
    float* __restrict__ red, int kq, int q0, int lane)
{
    float acc[HALF];
    #pragma unroll
    for (int q = 0; q < HALF; ++q) acc[q] = 0.0f;
    mm_seg<RPB,HALF>(rbb, wq, c0, a1, pr0s, acc);
    mm_seg<RPB,HALF>(rbb, wq, b0, c1, pr1s - r0l, acc);
    #pragma unroll
    for (int q = 0; q < HALF; ++q)
        red[(kq*32 + q0 + q)*64 + lane] = acc[q];
}

__global__ void __launch_bounds__(NTHR5, 1) rnn_loop_v5(Params p)
{
    cg::grid_group grid = cg::this_grid();
    const int tid  = threadIdx.x;
    const int lane = tid & 63;          // batch
    const int wv   = tid >> 6;          // 0..7
    const int kq   = __builtin_amdgcn_readfirstlane(wv & 3);
    const int grp  = __builtin_amdgcn_readfirstlane(wv >> 2);
    const int bi   = blockIdx.x;

    int r = 0;
    while (bi >= c5_cs[r+1]) ++r;
    const int lc    = bi - c5_cs[r];
    const int rpb   = c5_rpb[r];
    const int row0  = lc * rpb;
    const int nr    = min(rpb, c_rows[r] - row0);
    const int u0    = c_dst[r] + row0;          // original unit index base
    const int u0p   = c5_pdst[r] + row0;        // padded unit index base
    const int width = c_wid[r];
    const float tonic = c_ton[r];
    const int r0l = c_r0l[r];
    const int pr0s = c5_pr0s[r], pr1s = c5_pr1s[r];
    const float* __restrict__ wblk = p.Wc + c5_wb[r] + lc * width * rpb;

    __shared__ float red[4*32*64];     // [quarter][row<=32][batch]
    __shared__ float htile[32*65];     // padded transpose tile

    const int r2 = wv;                 // pointwise row group
    const int b  = lane;

    // ---- init: x to regs, h(0) to transposed hT0 ----
    float xreg[4] = {0.f,0.f,0.f,0.f};
    #pragma unroll
    for (int pi = 0; pi < 4; ++pi) {
        int pr = r2 + 8*pi;
        if (pr < nr) {
            int u = u0 + pr;
            xreg[pi] = p.xn[b*UNITS + u];
            p.hT0[b*HSTR + u0p + pr] = p.hn[b*UNITS + u];
        }
    }
    if (bi == 0) {                     // zero pad columns (hygiene; never read)
        for (int idx = tid; idx < 64*7; idx += NTHR5) {
            int bb2 = idx / 7, k = idx - bb2*7;
            int col = (k < 3) ? (665 + k) : (3225 + k);
            p.hT0[bb2*HSTR + col] = 0.0f;
            p.hT1[bb2*HSTR + col] = 0.0f;
        }
    }
    const bool outs_block = (bi >= 39 && bi < 103);   // gpe|stn|snr|thal[0:16]
    const int  ob = bi - 39;
    grid.sync();

    const int c0 = __builtin_amdgcn_readfirstlane((width * kq) >> 2);
    const int c1 = __builtin_amdgcn_readfirstlane((width * (kq + 1)) >> 2);
    const int q0 = __builtin_amdgcn_readfirstlane(grp * (rpb >> 1));
    const int a1 = min(c1, r0l), b0 = max(c0, r0l);
    const float* __restrict__ wq = wblk + q0;

    for (int t = 0; t < NSTEP; ++t) {
        const float* __restrict__ rb = (t & 1) ? p.hT1 : p.hT0;
        float* __restrict__ wb = (t & 1) ? p.hT0 : p.hT1;

        // readout for previous step (h(t-1) in rb, transposed read)
        if (outs_block && t > 0 && tid < 64) {
            float s = 0.0f;
            for (int jj = lane; jj < 359; jj += 64)
                s += rb[ob*HSTR + 2716 + jj] * p.out_w[jj];
            #pragma unroll
            for (int off = 32; off > 0; off >>= 1)
                s += __shfl_down(s, off, 64);
            if (lane == 0) p.out[HSZ + (long long)ob*NSTEP + (t-1)] = s;
        }

        // prefetch per-step strided inputs (latency hides under matmul)
        float nh[4] = {0.f,0.f,0.f,0.f}, ih[4] = {0.f,0.f,0.f,0.f};
        #pragma unroll
        for (int pi = 0; pi < 4; ++pi) {
            int pr = r2 + 8*pi;
            if (pr < nr) {
                int u = u0 + pr;
                nh[pi] = __builtin_nontemporal_load(&p.noise_hid[((long long)t*NBATCH + b)*UNITS + u]);
                ih[pi] = __builtin_nontemporal_load(&p.inhib[((long long)b*NSTEP + t)*UNITS + u]);
            }
        }
        const float inp_eff = p.inp[b*NSTEP + t] + NI_SCALE * p.noise_inp[t*NBATCH + b];
        const float cue_b   = p.cue[b*NSTEP + t];

        // ---- matmul: wave = (row-half grp, K-quarter kq), float4 hv loads ----
        const float* __restrict__ rbb = rb + lane*HSTR;
        if (r == 0)
            mm_do<16,8 >(rbb, wq, c0, a1, b0, c1, pr0s, pr1s, r0l, red, kq, q0, lane);
        else if (r == 1 || r == 6)
            mm_do<24,12>(rbb, wq, c0, a1, b0, c1, pr0s, pr1s, r0l, red, kq, q0, lane);
        else
            mm_do<32,16>(rbb, wq, c0, a1, b0, c1, pr0s, pr1s, r0l, red, kq, q0, lane);
        __syncthreads();

        // ---- reduce quarters (ascending) + pointwise ----
        #pragma unroll
        for (int pi = 0; pi < 4; ++pi) {
            int pr = r2 + 8*pi;
            if (pr < nr) {
                int u = u0 + pr;
                float mm = red[(0*32 + pr)*64 + b];
                mm += red[(1*32 + pr)*64 + b];
                mm += red[(2*32 + pr)*64 + b];
                mm += red[(3*32 + pr)*64 + b];
                float drive = mm + tonic;
                if (u < 665) drive += inp_eff * p.inp_w[u];
                if (u >= 2201 && u < 2713) drive += cue_b;
                drive += ih[pi];
                drive += NH_SCALE * nh[pi];
                float xv = xreg[pi];
                xv = xv + 0.1f*(drive - xv);
                xreg[pi] = xv;
                float h = fmaxf(xv, 0.0f);
                wb[b*HSTR + u0p + pr] = h;     // transposed state write
                htile[pr*65 + b] = h;
            }
        }
        __syncthreads();
        {
            // hs output: [b][t][u] (original unit indices)
            int rr = tid & 31, bb = tid >> 5;  // bb 0..15, four passes
            if (rr < nr) {
                #pragma unroll
                for (int rep = 0; rep < 4; ++rep) {
                    int bbb = bb + 16*rep;
                    long long o = (long long)bbb*(NSTEP*UNITS) + (long long)t*UNITS + (u0+rr);
                    __builtin_nontemporal_store(htile[rr*65 + bbb], &p.out[o]);
                }
            }
        }
        grid.sync();
    }

    // final readout: h(499) in hT0 (500 even)
    if (outs_block && tid < 64) {
        const float* __restrict__ rb = p.hT0;
        float s = 0.0f;
        for (int jj = lane; jj < 359; jj += 64)
            s += rb[ob*HSTR + 2716 + jj] * p.out_w[jj];
        #pragma unroll
        for (int off = 32; off > 0; off >>= 1)
            s += __shfl_down(s, off, 64);
        if (lane == 0) p.out[HSZ + (long long)ob*NSTEP + (NSTEP-1)] = s;
    }
}

// =============== round-0 fallback (verbatim logic, [unit][batch] h) ===============
__global__ void __launch_bounds__(256) rnn_loop_fb(Params p)
{
    cg::grid_group grid = cg::this_grid();
    const int tid  = threadIdx.x;
    const int lane = tid & 63;
    const int wv   = tid >> 6;
    const int bi   = blockIdx.x;

    int r = 0;
    while (bi >= c0_cs[r+1]) ++r;
    const int lc    = bi - c0_cs[r];
    const int row0  = lc * 8;
    const int nr    = min(8, c_rows[r] - row0);
    const int u0    = c_dst[r] + row0;
    const int width = c_wid[r];
    const float tonic = c_ton[r];
    const int r0s = c_r0s[r], r0l = c_r0l[r], r1s = c_r1s[r];
    const float* __restrict__ wr = p.Wc + c0_base[r] + row0 * width;

    __shared__ float red[4][8][64];
    __shared__ float htile[8*65];

    const int r2 = tid >> 6;
    const int b  = tid & 63;

    float xreg[2];
    #pragma unroll
    for (int pi = 0; pi < 2; ++pi) {
        int pr = r2 + 4*pi;
        xreg[pi] = 0.0f;
        if (pr < nr) {
            xreg[pi] = p.xn[b*UNITS + (u0+pr)];
            p.hT0[(u0+pr)*64 + b] = p.hn[b*UNITS + (u0+pr)];
        }
    }
    const bool outs_block = (bi >= 84 && bi < 148);
    grid.sync();

    const int c0 = (width * wv) >> 2;
    const int c1 = (width * (wv+1)) >> 2;
    const int a0 = c0, a1 = min(c1, r0l);
    const int b0 = max(c0, r0l), b1 = c1;

    for (int t = 0; t < NSTEP; ++t) {
        const float* __restrict__ rb = (t & 1) ? p.hT1 : p.hT0;
        float* __restrict__ wb = (t & 1) ? p.hT0 : p.hT1;

        if (outs_block && t > 0 && tid < 64) {
            int ob = bi - 84;
            float s = 0.0f;
            for (int jj = lane; jj < 359; jj += 64)
                s += rb[(2713+jj)*64 + ob] * p.out_w[jj];
            #pragma unroll
            for (int off = 32; off > 0; off >>= 1)
                s += __shfl_down(s, off, 64);
            if (lane == 0) p.out[HSZ + (long long)ob*NSTEP + (t-1)] = s;
        }

        float acc[8];
        #pragma unroll
        for (int q = 0; q < 8; ++q) acc[q] = 0.0f;

        #pragma unroll 4
        for (int c = a0; c < a1; ++c) {
            float hv = rb[(r0s + c)*64 + lane];
            #pragma unroll
            for (int q = 0; q < 8; ++q) acc[q] += wr[q*width + c] * hv;
        }
        #pragma unroll 4
        for (int c = b0; c < b1; ++c) {
            float hv = rb[(r1s + (c - r0l))*64 + lane];
            #pragma unroll
            for (int q = 0; q < 8; ++q) acc[q] += wr[q*width + c] * hv;
        }

        #pragma unroll
        for (int q = 0; q < 8; ++q) red[wv][q][lane] = acc[q];
        __syncthreads();

        const float inp_eff = p.inp[b*NSTEP + t] + NI_SCALE * p.noise_inp[t*NBATCH + b];
        const float cue_b   = p.cue[b*NSTEP + t];
        #pragma unroll
        for (int pi = 0; pi < 2; ++pi) {
            int pr = r2 + 4*pi;
            if (pr < nr) {
                int u = u0 + pr;
                float mm = red[0][pr][b] + red[1][pr][b] + red[2][pr][b] + red[3][pr][b];
                float drive = mm + tonic;
                if (u < 665) drive += inp_eff * p.inp_w[u];
                if (u >= 2201 && u < 2713) drive += cue_b;
                drive += p.inhib[((long long)b*NSTEP + t)*UNITS + u];
                drive += NH_SCALE * p.noise_hid[((long long)t*NBATCH + b)*UNITS + u];
                float xv = xreg[pi];
                xv = xv + 0.1f*(drive - xv);
                xreg[pi] = xv;
                float h = fmaxf(xv, 0.0f);
                wb[u*64 + b] = h;
                htile[pr*65 + b] = h;
            }
        }
        __syncthreads();
        {
            int rr = tid & 7, bb = tid >> 3;
            if (rr < nr) {
                long long o = (long long)bb*(NSTEP*UNITS) + (long long)t*UNITS + (u0+rr);
                p.out[o] = htile[rr*65 + bb];
                p.out[o + 32ll*NSTEP*UNITS] = htile[rr*65 + bb + 32];
            }
        }
        grid.sync();
    }

    if (outs_block && tid < 64) {
        int ob = bi - 84;
        const float* __restrict__ rb = p.hT0;
        float s = 0.0f;
        for (int jj = lane; jj < 359; jj += 64)
            s += rb[(2713+jj)*64 + ob] * p.out_w[jj];
        #pragma unroll
        for (int off = 32; off > 0; off >>= 1)
            s += __shfl_down(s, off, 64);
        if (lane == 0) p.out[HSZ + (long long)ob*NSTEP + (NSTEP-1)] = s;
    }
}

extern "C" void kernel_launch(void* const* d_in, const int* in_sizes, int n_in,
                              void* d_out, int out_size, void* d_ws, size_t ws_size,
                              hipStream_t stream)
{
    (void)in_sizes; (void)n_in; (void)out_size; (void)ws_size;
    const float* inp       = (const float*)d_in[0];
    const float* cue       = (const float*)d_in[1];
    const float* inhib     = (const float*)d_in[2];
    const float* hn        = (const float*)d_in[3];
    const float* xn        = (const float*)d_in[4];
    const float* noise_hid = (const float*)d_in[5];
    const float* noise_inp = (const float*)d_in[6];
    const float* str2str   = (const float*)d_in[7];
    const float* thal2alm  = (const float*)d_in[8];
    const float* thal2str  = (const float*)d_in[9];
    const float* alm2alm   = (const float*)d_in[10];
    const float* alm2str   = (const float*)d_in[11];
    const float* alm2thal  = (const float*)d_in[12];
    const float* str2snr   = (const float*)d_in[13];
    const float* str2gpe   = (const float*)d_in[14];
    const float* gpe2stn   = (const float*)d_in[15];
    const float* stn2snr   = (const float*)d_in[16];
    const float* snr2thal  = (const float*)d_in[17];
    const float* fsi2str   = (const float*)d_in[18];
    const float* thal2fsi  = (const float*)d_in[19];
    const float* alm2fsi   = (const float*)d_in[20];
    const float* fsi2fsi   = (const float*)d_in[21];
    const float* inp_w     = (const float*)d_in[22];
    const float* out_w     = (const float*)d_in[23];
    const int*   smask     = (const int*)d_in[24];

    float* Wct = (float*)d_ws;                  // v5 weights (or r0 on fallback)
    float* hT0 = Wct + WCT_FLOATS;              // 64*HSTR floats
    float* hT1 = hT0 + NBATCH*HSTR;             // total ws ~12.0 MB

    Params p;
    p.inp = inp; p.cue = cue; p.inhib = inhib; p.hn = hn; p.xn = xn;
    p.noise_hid = noise_hid; p.noise_inp = noise_inp;
    p.inp_w = inp_w; p.out_w = out_w; p.Wc = Wct;
    p.hT0 = hT0; p.hT1 = hT1; p.out = (float*)d_out;

    hipLaunchKernelGGL(build_w_v5, dim3((WCT_FLOATS+255)/256), dim3(256), 0, stream,
        str2str, thal2alm, thal2str, alm2alm, alm2str, alm2thal, str2snr, str2gpe,
        gpe2stn, stn2snr, snr2thal, fsi2str, thal2fsi, alm2fsi, fsi2fsi, smask, Wct);

    void* kargs[] = { &p };
    hipError_t ce = hipLaunchCooperativeKernel((void*)rnn_loop_v5,
                                               dim3(NBLK5), dim3(NTHR5), kargs, 0, stream);
    if (ce != hipSuccess) {
        (void)hipGetLastError();   // clear error state
        hipLaunchKernelGGL(build_w_r0, dim3((WC0_FLOATS+255)/256), dim3(256), 0, stream,
            str2str, thal2alm, thal2str, alm2alm, alm2str, alm2thal, str2snr, str2gpe,
            gpe2stn, stn2snr, snr2thal, fsi2str, thal2fsi, alm2fsi, fsi2fsi, smask, Wct);
        hipLaunchCooperativeKernel((void*)rnn_loop_fb,
                                   dim3(404), dim3(256), kargs, 0, stream);
    }
}

// Round 6
// 33840.930 us; speedup vs baseline: 2.4654x; 1.2373x over previous
//
// v6: no cg::grid.sync (no per-step L2 invalidate). h exchanged via
// agent-scope atomics ([unit][batch], coalesced); custom monotonic-counter
// grid barrier; weights stay L2/L1-resident. Bit-exact chain order kept
// (verified: v4/v5 reproduce reference absmax exactly). Round-0 fallback
// behind launch-error check.
#include <hip/hip_runtime.h>
#include <hip/hip_cooperative_groups.h>

namespace cg = cooperative_groups;

#define UNITS 3225
#define NBATCH 64
#define NSTEP 500
#define NH_SCALE 0.004472135954999579f   // 0.01*sqrt(2*0.1)
#define NI_SCALE 0.004472135954999579f
#define HSZ 103200000ll                  // 64*500*3225
#define WCT_FLOATS 2731520               // v6 transposed weights
#define WC0_FLOATS 2699776               // round-0 weights (fallback)
#define NBLK6 125
#define NTHR6 512

// ---- original geometry ----
__constant__ int   c_dst[7]  = {0,512,665,1177,1689,2201,2713};
__constant__ int   c_rows[7] = {512,153,512,512,512,512,512};
__constant__ int   c_wid[7]  = {1536,1024,256,512,768,871,1024};
__constant__ int   c_r0s[7]  = {0,512,256,665,0,1689,2201};
__constant__ int   c_r0l[7]  = {665,153,256,512,256,512,1024};
__constant__ int   c_r1s[7]  = {2201,2201,0,0,1177,2713,0};
__constant__ float c_ton[7]  = {0.1f,0.1f,0.6f,0.3f,0.6f,0.1f,0.1f};

// ---- v6 partition (= v5's, verified): str,fsi,gpe,stn,snr,thal,alm ----
__constant__ int   c6_rpb[7]  = {16,24,32,32,32,32,24};
__constant__ int   c6_cs[8]   = {0,32,39,55,71,87,103,125};
__constant__ int   c6_wb[8]   = {0,786432,958464,1089536,1351680,1744896,2190848,2731520};

// ---- round-0 fallback tables ----
__constant__ int   c0_cs[8]   = {0,64,84,148,212,276,340,404};
__constant__ int   c0_base[7] = {0,786432,943104,1074176,1336320,1729536,2175488};
__constant__ int   c0_cbase[8]= {0,786432,943104,1074176,1336320,1729536,2175488,2699776};

__device__ __forceinline__ float ht_clip(float w) {
    return fminf(fmaxf(w, 1e-10f), 1.0f);
}

__device__ __forceinline__ float agload(const float* pp) {
    return __hip_atomic_load(pp, __ATOMIC_RELAXED, __HIP_MEMORY_SCOPE_AGENT);
}
__device__ __forceinline__ void agstore(float* pp, float v) {
    __hip_atomic_store(pp, v, __ATOMIC_RELAXED, __HIP_MEMORY_SCOPE_AGENT);
}

// shared weight-value computation: region r, row-in-region i, compact col c
__device__ __forceinline__ float w_val(
    int r, int i, int c,
    const float* __restrict__ str2str, const float* __restrict__ thal2alm,
    const float* __restrict__ thal2str, const float* __restrict__ alm2alm,
    const float* __restrict__ alm2str, const float* __restrict__ alm2thal,
    const float* __restrict__ str2snr, const float* __restrict__ str2gpe,
    const float* __restrict__ gpe2stn, const float* __restrict__ stn2snr,
    const float* __restrict__ snr2thal, const float* __restrict__ fsi2str,
    const float* __restrict__ thal2fsi, const float* __restrict__ alm2fsi,
    const float* __restrict__ fsi2fsi, const int* __restrict__ smask)
{
    int r0l = c_r0l[r];
    int v = (c < r0l) ? (c_r0s[r] + c) : (c_r1s[r] + (c - r0l));
    int rv, j;
    if (v < 512)       { rv = 0; j = v; }
    else if (v < 665)  { rv = 1; j = v - 512; }
    else if (v < 1177) { rv = 2; j = v - 665; }
    else if (v < 1689) { rv = 3; j = v - 1177; }
    else if (v < 2201) { rv = 4; j = v - 1689; }
    else if (v < 2713) { rv = 5; j = v - 2201; }
    else               { rv = 6; j = v - 2713; }
    float val = 0.0f;
    switch (r) {
    case 0:
        if (rv == 0)      val = smask[i*512+j] ? -ht_clip(str2str[i*512+j]) : 0.0f;
        else if (rv == 1) val = -ht_clip(fsi2str[i*153+j]);
        else if (rv == 5) val = (i < 256) ? ht_clip(thal2str[i*512+j]) : 0.0f;
        else              val = (j < 359) ? ht_clip(alm2str[i*512+j]) : 0.0f;
        break;
    case 1:
        if (rv == 1)      val = -ht_clip(fsi2fsi[i*153+j]);
        else if (rv == 5) val = ht_clip(thal2fsi[i*512+j]);
        else              val = (j < 359) ? ht_clip(alm2fsi[i*512+j]) : 0.0f;
        break;
    case 2:
        val = (j >= 256) ? -ht_clip(str2gpe[i*512+j]) : 0.0f;
        break;
    case 3:
        val = -ht_clip(gpe2stn[i*512+j]);
        break;
    case 4:
        if (rv == 0) val = (j < 256) ? -ht_clip(str2snr[i*512+j]) : 0.0f;
        else         val = ht_clip(stn2snr[i*512+j]);
        break;
    case 5:
        if (rv == 4) val = -ht_clip(snr2thal[i*512+j]);
        else         val = (j < 359) ? ht_clip(alm2thal[i*512+j]) : 0.0f;
        break;
    default:
        if (rv == 5) val = ht_clip(thal2alm[i*512+j]);
        else         val = (j < 359) ? ht_clip(alm2alm[i*512+j]) : -ht_clip(alm2alm[i*512+j]);
        break;
    }
    return val;
}

#define WARGS                                                                  \
    const float* __restrict__ str2str, const float* __restrict__ thal2alm,     \
    const float* __restrict__ thal2str, const float* __restrict__ alm2alm,     \
    const float* __restrict__ alm2str, const float* __restrict__ alm2thal,     \
    const float* __restrict__ str2snr, const float* __restrict__ str2gpe,      \
    const float* __restrict__ gpe2stn, const float* __restrict__ stn2snr,      \
    const float* __restrict__ snr2thal, const float* __restrict__ fsi2str,     \
    const float* __restrict__ thal2fsi, const float* __restrict__ alm2fsi,     \
    const float* __restrict__ fsi2fsi, const int* __restrict__ smask
#define WPASS str2str, thal2alm, thal2str, alm2alm, alm2str, alm2thal,         \
    str2snr, str2gpe, gpe2stn, stn2snr, snr2thal, fsi2str, thal2fsi, alm2fsi,  \
    fsi2fsi, smask

// weights transposed per block: Wct[blockbase + c*rpb + q]; also zero barrier cnt
__global__ void build_w_v6(WARGS, float* __restrict__ Wct, unsigned* __restrict__ cnt)
{
    int tid = blockIdx.x * blockDim.x + threadIdx.x;
    if (tid == 0) { cnt[0] = 0u; }
    if (tid >= WCT_FLOATS) return;
    int r = 0;
    while (tid >= c6_wb[r+1]) ++r;
    int local = tid - c6_wb[r];
    int rpb   = c6_rpb[r];
    int width = c_wid[r];
    int bsz   = width * rpb;
    int blk   = local / bsz;
    int rem   = local - blk*bsz;
    int c     = rem / rpb;
    int q     = rem - c*rpb;
    int i     = blk*rpb + q;
    float val = 0.0f;
    if (i < c_rows[r]) val = w_val(r, i, c, WPASS);
    Wct[tid] = val;
}

// round-0 layout (fallback): Wc[blockrowbase + q*width + c]
__global__ void build_w_r0(WARGS, float* __restrict__ Wc)
{
    int tid = blockIdx.x * blockDim.x + threadIdx.x;
    if (tid >= WC0_FLOATS) return;
    int r = 0;
    while (tid >= c0_cbase[r+1]) ++r;
    int local = tid - c0_cbase[r];
    int width = c_wid[r];
    int row = local / width;
    int c = local - row * width;
    Wc[tid] = w_val(r, row, c, WPASS);
}

struct Params {
    const float* __restrict__ inp;
    const float* __restrict__ cue;
    const float* __restrict__ inhib;
    const float* __restrict__ hn;
    const float* __restrict__ xn;
    const float* __restrict__ noise_hid;
    const float* __restrict__ noise_inp;
    const float* __restrict__ inp_w;
    const float* __restrict__ out_w;
    const float* __restrict__ Wc;
    float* __restrict__ hT0;
    float* __restrict__ hT1;
    unsigned* __restrict__ cnt;
    float* __restrict__ out;
};

// grid barrier without cache maintenance: h traffic is agent-scope (bypasses
// L2), so visibility needs only vmcnt-drain + one atomic counter at L3.
__device__ __forceinline__ void gbarrier(unsigned* cnt, unsigned target)
{
    asm volatile("s_waitcnt vmcnt(0)" ::: "memory");  // this thread's h stores acked
    __syncthreads();                                   // all threads of block done
    if (threadIdx.x == 0) {
        __hip_atomic_fetch_add(cnt, 1u, __ATOMIC_RELAXED, __HIP_MEMORY_SCOPE_AGENT);
        while (__hip_atomic_load(cnt, __ATOMIC_RELAXED, __HIP_MEMORY_SCOPE_AGENT) < target)
            __builtin_amdgcn_s_sleep(2);
    }
    __syncthreads();
    asm volatile("" ::: "memory");                     // no load hoisting above poll
}

// BIT-EXACTNESS CONTRACT (verified: v4/v5 reproduce reference absmax exactly):
// per (row,quarter) one acc chain, segment A then B, strictly ascending c;
// quarters summed ascending; drive order mm+tonic -> inp -> cue -> inhib -> noise.
template<int RPB, int HALF>
__device__ __forceinline__ void mm_do(
    const float* __restrict__ rb, const float* __restrict__ wq,
    int c0, int a1, int b0, int c1, int r0s, int r1s, int r0l,
    float* __restrict__ red, int kq, int q0, int lane)
{
    float acc[HALF];
    #pragma unroll
    for (int q = 0; q < HALF; ++q) acc[q] = 0.0f;

    #pragma unroll 4
    for (int c = c0; c < a1; ++c) {
        float hv = agload(&rb[(r0s + c)*64 + lane]);
        #pragma unroll
        for (int g = 0; g < HALF/4; ++g) {
            const float4 w4 = *reinterpret_cast<const float4*>(&wq[c*RPB + 4*g]);
            acc[4*g+0] += w4.x * hv;
            acc[4*g+1] += w4.y * hv;
            acc[4*g+2] += w4.z * hv;
            acc[4*g+3] += w4.w * hv;
        }
    }
    #pragma unroll 4
    for (int c = b0; c < c1; ++c) {
        float hv = agload(&rb[(r1s + (c - r0l))*64 + lane]);
        #pragma unroll
        for (int g = 0; g < HALF/4; ++g) {
            const float4 w4 = *reinterpret_cast<const float4*>(&wq[c*RPB + 4*g]);
            acc[4*g+0] += w4.x * hv;
            acc[4*g+1] += w4.y * hv;
            acc[4*g+2] += w4.z * hv;
            acc[4*g+3] += w4.w * hv;
        }
    }
    #pragma unroll
    for (int q = 0; q < HALF; ++q)
        red[(kq*32 + q0 + q)*64 + lane] = acc[q];
}

__global__ void __launch_bounds__(NTHR6, 1) rnn_loop_v6(Params p)
{
    const int tid  = threadIdx.x;
    const int lane = tid & 63;          // batch
    const int wv   = tid >> 6;          // 0..7
    const int kq   = __builtin_amdgcn_readfirstlane(wv & 3);
    const int grp  = __builtin_amdgcn_readfirstlane(wv >> 2);
    const int bi   = blockIdx.x;

    int r = 0;
    while (bi >= c6_cs[r+1]) ++r;
    const int lc    = bi - c6_cs[r];
    const int rpb   = c6_rpb[r];
    const int row0  = lc * rpb;
    const int nr    = min(rpb, c_rows[r] - row0);
    const int u0    = c_dst[r] + row0;
    const int width = c_wid[r];
    const float tonic = c_ton[r];
    const int r0s = c_r0s[r], r0l = c_r0l[r], r1s = c_r1s[r];
    const float* __restrict__ wblk = p.Wc + c6_wb[r] + lc * width * rpb;

    __shared__ float red[4*32*64];     // [quarter][row<=32][batch]
    __shared__ float htile[32*65];     // padded transpose tile

    const int b = lane;

    // ---- init: x to regs, h(0) to hT0 ([unit][batch]) ----
    float xreg[4] = {0.f,0.f,0.f,0.f};
    #pragma unroll
    for (int pi = 0; pi < 4; ++pi) {
        int pr = wv + 8*pi;
        if (pr < nr) {
            int u = u0 + pr;
            xreg[pi] = p.xn[b*UNITS + u];
            agstore(&p.hT0[u*64 + b], p.hn[b*UNITS + u]);
        }
    }
    const bool outs_block = (bi >= 39 && bi < 103);   // gpe|stn|snr|thal blocks
    const int  ob = bi - 39;
    gbarrier(p.cnt, NBLK6);

    const int c0 = __builtin_amdgcn_readfirstlane((width * kq) >> 2);
    const int c1 = __builtin_amdgcn_readfirstlane((width * (kq + 1)) >> 2);
    const int q0 = __builtin_amdgcn_readfirstlane(grp * (rpb >> 1));
    const int a1 = min(c1, r0l), b0 = max(c0, r0l);
    const float* __restrict__ wq = wblk + q0;

    for (int t = 0; t < NSTEP; ++t) {
        const float* __restrict__ rb = (t & 1) ? p.hT1 : p.hT0;
        float* __restrict__ wb = (t & 1) ? p.hT0 : p.hT1;

        // readout for previous step (h(t-1) in rb)
        if (outs_block && t > 0 && tid < 64) {
            float s = 0.0f;
            for (int jj = lane; jj < 359; jj += 64)
                s += agload(&rb[(2713+jj)*64 + ob]) * p.out_w[jj];
            #pragma unroll
            for (int off = 32; off > 0; off >>= 1)
                s += __shfl_down(s, off, 64);
            if (lane == 0) p.out[HSZ + (long long)ob*NSTEP + (t-1)] = s;
        }

        // prefetch per-step strided inputs (latency hides under matmul)
        float nh[4] = {0.f,0.f,0.f,0.f}, ih[4] = {0.f,0.f,0.f,0.f};
        #pragma unroll
        for (int pi = 0; pi < 4; ++pi) {
            int pr = wv + 8*pi;
            if (pr < nr) {
                int u = u0 + pr;
                nh[pi] = __builtin_nontemporal_load(&p.noise_hid[((long long)t*NBATCH + b)*UNITS + u]);
                ih[pi] = __builtin_nontemporal_load(&p.inhib[((long long)b*NSTEP + t)*UNITS + u]);
            }
        }
        const float inp_eff = p.inp[b*NSTEP + t] + NI_SCALE * p.noise_inp[t*NBATCH + b];
        const float cue_b   = p.cue[b*NSTEP + t];

        // ---- matmul: wave = (row-half grp, K-quarter kq) ----
        if (r == 0)
            mm_do<16,8 >(rb, wq, c0, a1, b0, c1, r0s, r1s, r0l, red, kq, q0, lane);
        else if (r == 1 || r == 6)
            mm_do<24,12>(rb, wq, c0, a1, b0, c1, r0s, r1s, r0l, red, kq, q0, lane);
        else
            mm_do<32,16>(rb, wq, c0, a1, b0, c1, r0s, r1s, r0l, red, kq, q0, lane);
        __syncthreads();

        // ---- reduce quarters (ascending) + pointwise ----
        #pragma unroll
        for (int pi = 0; pi < 4; ++pi) {
            int pr = wv + 8*pi;
            if (pr < nr) {
                int u = u0 + pr;
                float mm = red[(0*32 + pr)*64 + b];
                mm += red[(1*32 + pr)*64 + b];
                mm += red[(2*32 + pr)*64 + b];
                mm += red[(3*32 + pr)*64 + b];
                float drive = mm + tonic;
                if (u < 665) drive += inp_eff * p.inp_w[u];
                if (u >= 2201 && u < 2713) drive += cue_b;
                drive += ih[pi];
                drive += NH_SCALE * nh[pi];
                float xv = xreg[pi];
                xv = xv + 0.1f*(drive - xv);
                xreg[pi] = xv;
                float h = fmaxf(xv, 0.0f);
                agstore(&wb[u*64 + b], h);     // cross-XCD visible, no L2 dirt
                htile[pr*65 + b] = h;
            }
        }
        __syncthreads();
        {
            // hs output: [b][t][u]
            int rr = tid & 31, bb = tid >> 5;  // bb 0..15, four passes
            if (rr < nr) {
                #pragma unroll
                for (int rep = 0; rep < 4; ++rep) {
                    int bbb = bb + 16*rep;
                    long long o = (long long)bbb*(NSTEP*UNITS) + (long long)t*UNITS + (u0+rr);
                    __builtin_nontemporal_store(htile[rr*65 + bbb], &p.out[o]);
                }
            }
        }
        gbarrier(p.cnt, (unsigned)NBLK6*(t+2));
    }

    // final readout: h(499) in hT0 (500 even)
    if (outs_block && tid < 64) {
        const float* __restrict__ rb = p.hT0;
        float s = 0.0f;
        for (int jj = lane; jj < 359; jj += 64)
            s += agload(&rb[(2713+jj)*64 + ob]) * p.out_w[jj];
        #pragma unroll
        for (int off = 32; off > 0; off >>= 1)
            s += __shfl_down(s, off, 64);
        if (lane == 0) p.out[HSZ + (long long)ob*NSTEP + (NSTEP-1)] = s;
    }
}

// =============== round-0 fallback (verbatim logic, cg grid sync) ===============
__global__ void __launch_bounds__(256) rnn_loop_fb(Params p)
{
    cg::grid_group grid = cg::this_grid();
    const int tid  = threadIdx.x;
    const int lane = tid & 63;
    const int wv   = tid >> 6;
    const int bi   = blockIdx.x;

    int r = 0;
    while (bi >= c0_cs[r+1]) ++r;
    const int lc    = bi - c0_cs[r];
    const int row0  = lc * 8;
    const int nr    = min(8, c_rows[r] - row0);
    const int u0    = c_dst[r] + row0;
    const int width = c_wid[r];
    const float tonic = c_ton[r];
    const int r0s = c_r0s[r], r0l = c_r0l[r], r1s = c_r1s[r];
    const float* __restrict__ wr = p.Wc + c0_base[r] + row0 * width;

    __shared__ float red[4][8][64];
    __shared__ float htile[8*65];

    const int r2 = tid >> 6;
    const int b  = tid & 63;

    float xreg[2];
    #pragma unroll
    for (int pi = 0; pi < 2; ++pi) {
        int pr = r2 + 4*pi;
        xreg[pi] = 0.0f;
        if (pr < nr) {
            xreg[pi] = p.xn[b*UNITS + (u0+pr)];
            p.hT0[(u0+pr)*64 + b] = p.hn[b*UNITS + (u0+pr)];
        }
    }
    const bool outs_block = (bi >= 84 && bi < 148);
    grid.sync();

    const int c0 = (width * wv) >> 2;
    const int c1 = (width * (wv+1)) >> 2;
    const int a0 = c0, a1 = min(c1, r0l);
    const int b0 = max(c0, r0l), b1 = c1;

    for (int t = 0; t < NSTEP; ++t) {
        const float* __restrict__ rb = (t & 1) ? p.hT1 : p.hT0;
        float* __restrict__ wb = (t & 1) ? p.hT0 : p.hT1;

        if (outs_block && t > 0 && tid < 64) {
            int ob = bi - 84;
            float s = 0.0f;
            for (int jj = lane; jj < 359; jj += 64)
                s += rb[(2713+jj)*64 + ob] * p.out_w[jj];
            #pragma unroll
            for (int off = 32; off > 0; off >>= 1)
                s += __shfl_down(s, off, 64);
            if (lane == 0) p.out[HSZ + (long long)ob*NSTEP + (t-1)] = s;
        }

        float acc[8];
        #pragma unroll
        for (int q = 0; q < 8; ++q) acc[q] = 0.0f;

        #pragma unroll 4
        for (int c = a0; c < a1; ++c) {
            float hv = rb[(r0s + c)*64 + lane];
            #pragma unroll
            for (int q = 0; q < 8; ++q) acc[q] += wr[q*width + c] * hv;
        }
        #pragma unroll 4
        for (int c = b0; c < b1; ++c) {
            float hv = rb[(r1s + (c - r0l))*64 + lane];
            #pragma unroll
            for (int q = 0; q < 8; ++q) acc[q] += wr[q*width + c] * hv;
        }

        #pragma unroll
        for (int q = 0; q < 8; ++q) red[wv][q][lane] = acc[q];
        __syncthreads();

        const float inp_eff = p.inp[b*NSTEP + t] + NI_SCALE * p.noise_inp[t*NBATCH + b];
        const float cue_b   = p.cue[b*NSTEP + t];
        #pragma unroll
        for (int pi = 0; pi < 2; ++pi) {
            int pr = r2 + 4*pi;
            if (pr < nr) {
                int u = u0 + pr;
                float mm = red[0][pr][b] + red[1][pr][b] + red[2][pr][b] + red[3][pr][b];
                float drive = mm + tonic;
                if (u < 665) drive += inp_eff * p.inp_w[u];
                if (u >= 2201 && u < 2713) drive += cue_b;
                drive += p.inhib[((long long)b*NSTEP + t)*UNITS + u];
                drive += NH_SCALE * p.noise_hid[((long long)t*NBATCH + b)*UNITS + u];
                float xv = xreg[pi];
                xv = xv + 0.1f*(drive - xv);
                xreg[pi] = xv;
                float h = fmaxf(xv, 0.0f);
                wb[u*64 + b] = h;
                htile[pr*65 + b] = h;
            }
        }
        __syncthreads();
        {
            int rr = tid & 7, bb = tid >> 3;
            if (rr < nr) {
                long long o = (long long)bb*(NSTEP*UNITS) + (long long)t*UNITS + (u0+rr);
                p.out[o] = htile[rr*65 + bb];
                p.out[o + 32ll*NSTEP*UNITS] = htile[rr*65 + bb + 32];
            }
        }
        grid.sync();
    }

    if (outs_block && tid < 64) {
        int ob = bi - 84;
        const float* __restrict__ rb = p.hT0;
        float s = 0.0f;
        for (int jj = lane; jj < 359; jj += 64)
            s += rb[(2713+jj)*64 + ob] * p.out_w[jj];
        #pragma unroll
        for (int off = 32; off > 0; off >>= 1)
            s += __shfl_down(s, off, 64);
        if (lane == 0) p.out[HSZ + (long long)ob*NSTEP + (NSTEP-1)] = s;
    }
}

extern "C" void kernel_launch(void* const* d_in, const int* in_sizes, int n_in,
                              void* d_out, int out_size, void* d_ws, size_t ws_size,
                              hipStream_t stream)
{
    (void)in_sizes; (void)n_in; (void)out_size; (void)ws_size;
    const float* inp       = (const float*)d_in[0];
    const float* cue       = (const float*)d_in[1];
    const float* inhib     = (const float*)d_in[2];
    const float* hn        = (const float*)d_in[3];
    const float* xn        = (const float*)d_in[4];
    const float* noise_hid = (const float*)d_in[5];
    const float* noise_inp = (const float*)d_in[6];
    const float* str2str   = (const float*)d_in[7];
    const float* thal2alm  = (const float*)d_in[8];
    const float* thal2str  = (const float*)d_in[9];
    const float* alm2alm   = (const float*)d_in[10];
    const float* alm2str   = (const float*)d_in[11];
    const float* alm2thal  = (const float*)d_in[12];
    const float* str2snr   = (const float*)d_in[13];
    const float* str2gpe   = (const float*)d_in[14];
    const float* gpe2stn   = (const float*)d_in[15];
    const float* stn2snr   = (const float*)d_in[16];
    const float* snr2thal  = (const float*)d_in[17];
    const float* fsi2str   = (const float*)d_in[18];
    const float* thal2fsi  = (const float*)d_in[19];
    const float* alm2fsi   = (const float*)d_in[20];
    const float* fsi2fsi   = (const float*)d_in[21];
    const float* inp_w     = (const float*)d_in[22];
    const float* out_w     = (const float*)d_in[23];
    const int*   smask     = (const int*)d_in[24];

    float*    Wct = (float*)d_ws;
    float*    hT0 = Wct + WCT_FLOATS;           // [UNITS][64]
    float*    hT1 = hT0 + UNITS*64;
    unsigned* cnt = (unsigned*)(hT1 + UNITS*64);  // total ws ~12.58 MB

    Params p;
    p.inp = inp; p.cue = cue; p.inhib = inhib; p.hn = hn; p.xn = xn;
    p.noise_hid = noise_hid; p.noise_inp = noise_inp;
    p.inp_w = inp_w; p.out_w = out_w; p.Wc = Wct;
    p.hT0 = hT0; p.hT1 = hT1; p.cnt = cnt; p.out = (float*)d_out;

    hipLaunchKernelGGL(build_w_v6, dim3((WCT_FLOATS+255)/256), dim3(256), 0, stream,
        str2str, thal2alm, thal2str, alm2alm, alm2str, alm2thal, str2snr, str2gpe,
        gpe2stn, stn2snr, snr2thal, fsi2str, thal2fsi, alm2fsi, fsi2fsi, smask, Wct, cnt);

    void* kargs[] = { &p };
    // cooperative launch only for the co-residency guarantee (no cg sync inside)
    hipError_t ce = hipLaunchCooperativeKernel((void*)rnn_loop_v6,
                                               dim3(NBLK6), dim3(NTHR6), kargs, 0, stream);
    if (ce != hipSuccess) {
        (void)hipGetLastError();   // clear error state
        hipLaunchKernelGGL(build_w_r0, dim3((WC0_FLOATS+255)/256), dim3(256), 0, stream,
            str2str, thal2alm, thal2str, alm2alm, alm2str, alm2thal, str2snr, str2gpe,
            gpe2stn, stn2snr, snr2thal, fsi2str, thal2fsi, alm2fsi, fsi2fsi, smask, Wct);
        hipLaunchCooperativeKernel((void*)rnn_loop_fb,
                                   dim3(404), dim3(256), kargs, 0, stream);
    }
}